// Round 2
// baseline (238.514 us; speedup 1.0000x reference)
//
#include <hip/hip_runtime.h>
#include <stdint.h>

#define NIMG 32
#define CH 32
#define HH 160
#define WW 160
#define HWL (HH*WW)            // 25600
#define PRS 164                // padded row stride (words)
#define PHH 162
#define PIMG (PHH*PRS)         // 26568 words per padded image
#define NPIX (NIMG*HWL)        // 819200 pixels

// workspace layout (bytes)
#define OFF_P     0
#define OFF_Y     3400704                    // P: 32*26568*4
#define OFF_INNER (OFF_Y + 52428800)         // Y: int16
#define OFF_WP    (OFF_INNER + 52428800)     // inner: bf16
#define OFF_CORR  (OFF_WP + 2304)
#define OFF_SC    (OFF_CORR + 2304)
#define OFF_SB    (OFF_SC + 128)             // 64 StatLines x 128 B

struct StatLine {                            // one 128B line per channel: parallel atomics
  int s1; int pad0; unsigned long long s2; char pad[112];
};

__device__ inline unsigned short f2bf(float f) {   // RNE float->bf16
  unsigned u = __float_as_uint(f);
  u += 0x7fffu + ((u >> 16) & 1u);
  return (unsigned short)(u >> 16);
}

// ---------------- pack x bits (blocks 0..3320) + prep tail block (3321)
__global__ __launch_bounds__(256) void pack_prep(const float* __restrict__ x,
    const float* __restrict__ w1, const float* __restrict__ w2,
    uint32_t* __restrict__ P, uint32_t* __restrict__ WP, int* __restrict__ CORR,
    float* __restrict__ SC, StatLine* __restrict__ SB)
{
  const int tid = threadIdx.x;
  if (blockIdx.x == 3321) {
    // ---- prep: zero stats, weight scales, bit-pack, border corrections
    int* z = (int*)SB;
    for (int i = tid; i < 2048; i += 256) z[i] = 0;
    __shared__ float red[256];
    for (int cv = 0; cv < 2; ++cv) {
      const float* w = cv ? w2 : w1;
      float s = 0.f;
      for (int i = tid; i < 9216; i += 256) s += fabsf(w[i]);
      red[tid] = s;
      __syncthreads();
      for (int st = 128; st > 0; st >>= 1) {
        if (tid < st) red[tid] += red[tid + st];
        __syncthreads();
      }
      if (tid == 0) SC[cv] = red[0] / 9216.0f;
      for (int i = tid; i < 288; i += 256) {
        int co = i / 9, t = i - co * 9;
        uint32_t b = 0;
        for (int ci = 0; ci < 32; ++ci)
          b |= (w[(co * 32 + ci) * 9 + t] > 0.0f) ? (1u << ci) : 0u;
        WP[cv * 288 + i] = b;
      }
      __syncthreads();
      for (int i = tid; i < 288; i += 256) {
        int cls = i / 32, co = i - cls * 32;
        int hc = cls / 3, wc = cls - hc * 3;
        int corr = 0;
        for (int t = 0; t < 9; ++t) {
          int dy = t / 3 - 1, dx = t % 3 - 1;
          bool inval = (hc == 0 && dy == -1) || (hc == 2 && dy == 1) ||
                       (wc == 0 && dx == -1) || (wc == 2 && dx == 1);
          if (inval) corr += 32 - 2 * __popc(WP[cv * 288 + co * 9 + t]);
        }
        CORR[cv * 288 + cls * 32 + co] = corr;
      }
      __syncthreads();
    }
    return;
  }
  // ---- pack: one padded word per thread (halo words -> 0)
  int g = blockIdx.x * 256 + tid;           // 0 .. 32*PIMG-1
  int n = g / PIMG;
  int r = g - n * PIMG;
  int pr = r / PRS;
  int pc = r - pr * PRS;
  uint32_t bits = 0;
  int h = pr - 1, w = pc - 1;
  if (h >= 0 && h < HH && w >= 0 && w < WW) {
    const float* xp = x + (size_t)n * CH * HWL + h * WW + w;
    #pragma unroll 8
    for (int c = 0; c < 32; ++c)
      bits |= (xp[(size_t)c * HWL] > 0.0f) ? (1u << c) : 0u;
  }
  P[g] = bits;
}

// ---------------- binary conv (xor+popcount), 4 px x 32 co per thread, fused stats
__global__ __launch_bounds__(256) void conv_stats(const uint32_t* __restrict__ P,
    const uint32_t* __restrict__ WP, const int* __restrict__ CORR,
    short* __restrict__ Y, StatLine* __restrict__ sb)
{
  __shared__ uint32_t wsh[288];
  __shared__ int csh[288];
  __shared__ int ls1[32], ls2[32];
  const int tid = threadIdx.x;
  for (int i = tid; i < 288; i += 256) { wsh[i] = WP[i]; csh[i] = CORR[i]; }
  if (tid < 32) { ls1[tid] = 0; ls2[tid] = 0; }
  __syncthreads();

  int g = blockIdx.x * 256 + tid;           // over 32*160*40 = 204800
  int w4 = g % 40;
  int t1 = g / 40;
  int h = t1 % 160;
  int n = t1 / 160;

  const uint32_t* base = P + n * PIMG + h * PRS + w4 * 4;
  uint32_t r[3][6];
  #pragma unroll
  for (int dy = 0; dy < 3; ++dy) {
    uint4 a = *reinterpret_cast<const uint4*>(base + dy * PRS);
    uint2 b = *reinterpret_cast<const uint2*>(base + dy * PRS + 4);
    r[dy][0] = a.x; r[dy][1] = a.y; r[dy][2] = a.z; r[dy][3] = a.w;
    r[dy][4] = b.x; r[dy][5] = b.y;
  }

  int rowc = (h == 0) ? 0 : ((h == 159) ? 6 : 3);
  int cls0  = rowc + ((w4 == 0) ? 0 : 1);
  int cls12 = rowc + 1;
  int cls3  = rowc + ((w4 == 39) ? 2 : 1);
  int lane = tid & 63;

  short* yb = Y + (size_t)n * CH * HWL + h * WW + w4 * 4;

  for (int co = 0; co < 32; ++co) {
    uint32_t wv[9];
    #pragma unroll
    for (int t = 0; t < 9; ++t) wv[t] = wsh[co * 9 + t];
    int a0 = 0, a1 = 0, a2 = 0, a3 = 0;
    #pragma unroll
    for (int dy = 0; dy < 3; ++dy) {
      #pragma unroll
      for (int dx = 0; dx < 3; ++dx) {
        uint32_t wvv = wv[dy * 3 + dx];
        a0 += __popc(r[dy][0 + dx] ^ wvv);
        a1 += __popc(r[dy][1 + dx] ^ wvv);
        a2 += __popc(r[dy][2 + dx] ^ wvv);
        a3 += __popc(r[dy][3 + dx] ^ wvv);
      }
    }
    int d0 = 288 - 2 * a0 - csh[cls0 * 32 + co];
    int d1 = 288 - 2 * a1 - csh[cls12 * 32 + co];
    int d2 = 288 - 2 * a2 - csh[cls12 * 32 + co];
    int d3 = 288 - 2 * a3 - csh[cls3 * 32 + co];
    *reinterpret_cast<short4*>(yb + (size_t)co * HWL) =
        make_short4((short)d0, (short)d1, (short)d2, (short)d3);
    // fused per-channel stats: wave reduce -> LDS
    int ds = d0 + d1 + d2 + d3;
    int sq = d0 * d0 + d1 * d1 + d2 * d2 + d3 * d3;
    #pragma unroll
    for (int off = 32; off > 0; off >>= 1) {
      ds += __shfl_down(ds, off);
      sq += __shfl_down(sq, off);
    }
    if (lane == 0) { atomicAdd(&ls1[co], ds); atomicAdd(&ls2[co], sq); }
  }
  __syncthreads();
  if (tid < 32) {
    atomicAdd(&sb[tid].s1, ls1[tid]);
    atomicAdd(&sb[tid].s2, (unsigned long long)(long long)ls2[tid]);
  }
}

// ---------------- BN1 + residual -> inner(bf16) + repack bits; A,B derived in-block
__global__ __launch_bounds__(256) void bnres_pack(const short* __restrict__ Y,
    const float* __restrict__ x, const float* __restrict__ SCp,
    const StatLine* __restrict__ sb, const float* __restrict__ gamma,
    const float* __restrict__ beta, unsigned short* __restrict__ INNER,
    uint32_t* __restrict__ P)
{
  __shared__ float Ash[32], Bsh[32];
  const int tid = threadIdx.x;
  if (tid < 32) {
    double sc = (double)SCp[0];
    double m  = sc * (double)sb[tid].s1 / (double)NPIX;
    double ms = sc * sc * (double)(long long)sb[tid].s2 / (double)NPIX;
    double var = ms - m * m;
    float inv = (float)(1.0 / sqrt(var + 1e-5));
    float gm = gamma[tid];
    Ash[tid] = gm * inv * (float)sc;
    Bsh[tid] = beta[tid] - gm * inv * (float)m;
  }
  __syncthreads();
  int g = blockIdx.x * 256 + tid;            // 4 px per thread
  int p0 = g * 4;
  int n = p0 / HWL;
  int i = p0 - n * HWL;
  size_t base = (size_t)n * CH * HWL + i;
  uint32_t b0 = 0, b1 = 0, b2 = 0, b3 = 0;
  #pragma unroll 4
  for (int c = 0; c < 32; ++c) {
    size_t idx = base + (size_t)c * HWL;
    short4 y4 = *reinterpret_cast<const short4*>(Y + idx);
    float4 x4 = *reinterpret_cast<const float4*>(x + idx);
    float A = Ash[c], B = Bsh[c];
    float v0 = fmaf(A, (float)y4.x, B) + x4.x;
    float v1 = fmaf(A, (float)y4.y, B) + x4.y;
    float v2 = fmaf(A, (float)y4.z, B) + x4.z;
    float v3 = fmaf(A, (float)y4.w, B) + x4.w;
    ushort4 o; o.x = f2bf(v0); o.y = f2bf(v1); o.z = f2bf(v2); o.w = f2bf(v3);
    *reinterpret_cast<ushort4*>(INNER + idx) = o;
    uint32_t m = 1u << c;
    if (v0 > 0.f) b0 |= m;
    if (v1 > 0.f) b1 |= m;
    if (v2 > 0.f) b2 |= m;
    if (v3 > 0.f) b3 |= m;
  }
  int h = i / WW, w = i - (i / WW) * WW;
  uint32_t* pw = P + n * PIMG + (h + 1) * PRS + (w + 1);
  pw[0] = b0; pw[1] = b1; pw[2] = b2; pw[3] = b3;
}

// ---------------- BN2 + residual(inner bf16) -> out fp32; A,B derived in-block
__global__ __launch_bounds__(256) void bnres_final(const short* __restrict__ Y,
    const unsigned short* __restrict__ INNER, const float* __restrict__ SCp,
    const StatLine* __restrict__ sb, const float* __restrict__ gamma,
    const float* __restrict__ beta, float* __restrict__ out)
{
  __shared__ float Ash[32], Bsh[32];
  const int tid = threadIdx.x;
  if (tid < 32) {
    double sc = (double)SCp[0];
    double m  = sc * (double)sb[tid].s1 / (double)NPIX;
    double ms = sc * sc * (double)(long long)sb[tid].s2 / (double)NPIX;
    double var = ms - m * m;
    float inv = (float)(1.0 / sqrt(var + 1e-5));
    float gm = gamma[tid];
    Ash[tid] = gm * inv * (float)sc;
    Bsh[tid] = beta[tid] - gm * inv * (float)m;
  }
  __syncthreads();
  int g = blockIdx.x * 256 + tid;            // 4 px per thread
  int p0 = g * 4;
  int n = p0 / HWL;
  int i = p0 - n * HWL;
  size_t base = (size_t)n * CH * HWL + i;
  #pragma unroll 4
  for (int c = 0; c < 32; ++c) {
    size_t idx = base + (size_t)c * HWL;
    short4 y4 = *reinterpret_cast<const short4*>(Y + idx);
    ushort4 ib = *reinterpret_cast<const ushort4*>(INNER + idx);
    float A = Ash[c], B = Bsh[c];
    float4 o;
    o.x = fmaf(A, (float)y4.x, B) + __uint_as_float((uint32_t)ib.x << 16);
    o.y = fmaf(A, (float)y4.y, B) + __uint_as_float((uint32_t)ib.y << 16);
    o.z = fmaf(A, (float)y4.z, B) + __uint_as_float((uint32_t)ib.z << 16);
    o.w = fmaf(A, (float)y4.w, B) + __uint_as_float((uint32_t)ib.w << 16);
    *reinterpret_cast<float4*>(out + idx) = o;
  }
}

extern "C" void kernel_launch(void* const* d_in, const int* in_sizes, int n_in,
                              void* d_out, int out_size, void* d_ws, size_t ws_size,
                              hipStream_t stream)
{
  (void)in_sizes; (void)n_in; (void)out_size; (void)ws_size;
  const float* x  = (const float*)d_in[0];
  const float* w1 = (const float*)d_in[1];
  const float* g1 = (const float*)d_in[2];
  const float* b1 = (const float*)d_in[3];
  const float* w2 = (const float*)d_in[4];
  const float* g2 = (const float*)d_in[5];
  const float* b2 = (const float*)d_in[6];
  float* out = (float*)d_out;
  char* ws = (char*)d_ws;

  uint32_t*       P     = (uint32_t*)(ws + OFF_P);
  short*          Y     = (short*)(ws + OFF_Y);
  unsigned short* INNER = (unsigned short*)(ws + OFF_INNER);
  uint32_t*       WP    = (uint32_t*)(ws + OFF_WP);
  int*            CORR  = (int*)(ws + OFF_CORR);
  float*          SC    = (float*)(ws + OFF_SC);
  StatLine*       SB    = (StatLine*)(ws + OFF_SB);

  pack_prep<<<3322, 256, 0, stream>>>(x, w1, w2, P, WP, CORR, SC, SB);
  conv_stats<<<800, 256, 0, stream>>>(P, WP, CORR, Y, SB);
  bnres_pack<<<800, 256, 0, stream>>>(Y, x, SC, SB, g1, b1, INNER, P);
  conv_stats<<<800, 256, 0, stream>>>(P, WP + 288, CORR + 288, Y, SB + 32);
  bnres_final<<<800, 256, 0, stream>>>(Y, INNER, SC + 1, SB + 32, g2, b2, out);
}